// Round 11
// baseline (26.801 us; speedup 1.0000x reference)
//
#include <hip/hip_runtime.h>

#define B_ 8
#define S_ 1024
#define D_ 2048
#define E_ 2
#define NROWS (E_ * D_ + E_)   // 4098 reduction rows (W rows + bias rows)

typedef float f32x4 __attribute__((ext_vector_type(4)));

__device__ inline float wave_reduce_sum(float v) {
    #pragma unroll
    for (int off = 32; off > 0; off >>= 1) v += __shfl_down(v, off, 64);
    return v;
}
__device__ inline float wave_reduce_max(float v) {
    #pragma unroll
    for (int off = 32; off > 0; off >>= 1) v = fmaxf(v, __shfl_down(v, off, 64));
    return v;
}
__device__ inline float dot4(f32x4 a, f32x4 b) {
    return a.x * b.x + a.y * b.y + a.z * b.z + a.w * b.w;
}

// ---------- kernel 1: Wsum[e,d] = sum_h W[e,d,h]; bsum[e] = sum_h b[e,h] ----------
// One WAVE per row (D=2048 floats = 8 f32x4/lane). 4 waves/block, no barriers.
__global__ __launch_bounds__(256) void reduce_rows_kernel(
        const float* __restrict__ W, const float* __restrict__ bvec,
        float* __restrict__ Wsum, float* __restrict__ bsum) {
    const int wave = threadIdx.x >> 6, lane = threadIdx.x & 63;
    const int row = blockIdx.x * 4 + wave;
    if (row >= NROWS) return;
    const float* src = (row < E_ * D_) ? (W + (size_t)row * D_)
                                       : (bvec + (size_t)(row - E_ * D_) * D_);
    const f32x4* s4 = (const f32x4*)src;
    float s = 0.0f;
    #pragma unroll
    for (int j = 0; j < 8; ++j) {
        f32x4 v = __builtin_nontemporal_load(&s4[lane + j * 64]);  // W streamed once
        s += (v.x + v.y) + (v.z + v.w);
    }
    s = wave_reduce_sum(s);
    if (lane == 0) {
        if (row < E_ * D_) Wsum[row] = s;
        else               bsum[row - E_ * D_] = s;
    }
}

// ---------- kernel 2: per-token gate + selected-expert row-sum ----------
// 512 blocks x 16 tokens (4 tokens/wave): staging traffic halved vs 1024-block
// version, LDS weight reads amortized over 4 tokens. First half of each token's
// x prefetched into regs before staging (in flight across stage + barrier).
__global__ __launch_bounds__(256, 2) void token_kernel(
        const float* __restrict__ x, const float* __restrict__ wg,
        const float* __restrict__ Wsum, const float* __restrict__ bsum,
        float* __restrict__ y) {
    __shared__ float lw0[D_], lw1[D_], lg0[D_], lg1[D_];   // 32 KB -> 2 blocks/CU
    const int tid = threadIdx.x;
    const int wave = tid >> 6, lane = tid & 63;
    const int tbase = blockIdx.x * 16 + wave * 4;          // 4 tokens per wave

    // ---- issue x first-half prefetch FIRST (independent of LDS) ----
    f32x4 xr0[4], xr1[4], xr2[4], xr3[4];                  // 64 VGPRs of x in flight
    {
        const f32x4* x0p = (const f32x4*)(x + (size_t)(tbase + 0) * D_);
        const f32x4* x1p = (const f32x4*)(x + (size_t)(tbase + 1) * D_);
        const f32x4* x2p = (const f32x4*)(x + (size_t)(tbase + 2) * D_);
        const f32x4* x3p = (const f32x4*)(x + (size_t)(tbase + 3) * D_);
        #pragma unroll
        for (int j = 0; j < 4; ++j) {
            const int i = lane + j * 64;
            xr0[j] = __builtin_nontemporal_load(&x0p[i]);
            xr1[j] = __builtin_nontemporal_load(&x1p[i]);
            xr2[j] = __builtin_nontemporal_load(&x2p[i]);
            xr3[j] = __builtin_nontemporal_load(&x3p[i]);
        }
    }

    // ---- stage: Wsum rows + de-interleaved wg columns (overlaps x loads) ----
    {
        const f32x4* w0g = (const f32x4*)(Wsum);
        const f32x4* w1g = (const f32x4*)(Wsum + D_);
        const f32x4* wgg = (const f32x4*)(wg);             // [D,2] interleaved
        f32x4* l0 = (f32x4*)lw0; f32x4* l1 = (f32x4*)lw1;
        f32x4* g0 = (f32x4*)lg0; f32x4* g1 = (f32x4*)lg1;
        #pragma unroll
        for (int i = tid; i < D_ / 4; i += 256) {
            l0[i] = w0g[i];
            l1[i] = w1g[i];
            f32x4 u = wgg[2 * i];
            f32x4 v = wgg[2 * i + 1];
            f32x4 a, b;
            a.x = u.x; a.y = u.z; a.z = v.x; a.w = v.z;    // expert-0 gate col
            b.x = u.y; b.y = u.w; b.z = v.y; b.w = v.w;    // expert-1 gate col
            g0[i] = a;
            g1[i] = b;
        }
    }
    __syncthreads();

    const f32x4* l0r = (const f32x4*)lw0;
    const f32x4* l1r = (const f32x4*)lw1;
    const f32x4* c0r = (const f32x4*)lg0;
    const f32x4* c1r = (const f32x4*)lg1;

    // acc[t]: d0,d1,g0,g1 — fully unrolled, static indexing only
    float d0_0 = 0, d1_0 = 0, g0_0 = 0, g1_0 = 0;
    float d0_1 = 0, d1_1 = 0, g0_1 = 0, g1_1 = 0;
    float d0_2 = 0, d1_2 = 0, g0_2 = 0, g1_2 = 0;
    float d0_3 = 0, d1_3 = 0, g0_3 = 0, g1_3 = 0;

    // ---- first half: x from registers ----
    #pragma unroll
    for (int j = 0; j < 4; ++j) {
        const int i = lane + j * 64;
        f32x4 a = l0r[i], c = l1r[i], u = c0r[i], v = c1r[i];
        d0_0 += dot4(xr0[j], a); d1_0 += dot4(xr0[j], c);
        g0_0 += dot4(xr0[j], u); g1_0 += dot4(xr0[j], v);
        d0_1 += dot4(xr1[j], a); d1_1 += dot4(xr1[j], c);
        g0_1 += dot4(xr1[j], u); g1_1 += dot4(xr1[j], v);
        d0_2 += dot4(xr2[j], a); d1_2 += dot4(xr2[j], c);
        g0_2 += dot4(xr2[j], u); g1_2 += dot4(xr2[j], v);
        d0_3 += dot4(xr3[j], a); d1_3 += dot4(xr3[j], c);
        g0_3 += dot4(xr3[j], u); g1_3 += dot4(xr3[j], v);
    }
    // ---- second half: x streamed ----
    {
        const f32x4* x0p = (const f32x4*)(x + (size_t)(tbase + 0) * D_);
        const f32x4* x1p = (const f32x4*)(x + (size_t)(tbase + 1) * D_);
        const f32x4* x2p = (const f32x4*)(x + (size_t)(tbase + 2) * D_);
        const f32x4* x3p = (const f32x4*)(x + (size_t)(tbase + 3) * D_);
        #pragma unroll
        for (int j = 4; j < 8; ++j) {
            const int i = lane + j * 64;
            f32x4 xv0 = __builtin_nontemporal_load(&x0p[i]);
            f32x4 xv1 = __builtin_nontemporal_load(&x1p[i]);
            f32x4 xv2 = __builtin_nontemporal_load(&x2p[i]);
            f32x4 xv3 = __builtin_nontemporal_load(&x3p[i]);
            f32x4 a = l0r[i], c = l1r[i], u = c0r[i], v = c1r[i];
            d0_0 += dot4(xv0, a); d1_0 += dot4(xv0, c);
            g0_0 += dot4(xv0, u); g1_0 += dot4(xv0, v);
            d0_1 += dot4(xv1, a); d1_1 += dot4(xv1, c);
            g0_1 += dot4(xv1, u); g1_1 += dot4(xv1, v);
            d0_2 += dot4(xv2, a); d1_2 += dot4(xv2, c);
            g0_2 += dot4(xv2, u); g1_2 += dot4(xv2, v);
            d0_3 += dot4(xv3, a); d1_3 += dot4(xv3, c);
            g0_3 += dot4(xv3, u); g1_3 += dot4(xv3, v);
        }
    }

    d0_0 = wave_reduce_sum(d0_0); d1_0 = wave_reduce_sum(d1_0);
    g0_0 = wave_reduce_sum(g0_0); g1_0 = wave_reduce_sum(g1_0);
    d0_1 = wave_reduce_sum(d0_1); d1_1 = wave_reduce_sum(d1_1);
    g0_1 = wave_reduce_sum(g0_1); g1_1 = wave_reduce_sum(g1_1);
    d0_2 = wave_reduce_sum(d0_2); d1_2 = wave_reduce_sum(d1_2);
    g0_2 = wave_reduce_sum(g0_2); g1_2 = wave_reduce_sum(g1_2);
    d0_3 = wave_reduce_sum(d0_3); d1_3 = wave_reduce_sum(d1_3);
    g0_3 = wave_reduce_sum(g0_3); g1_3 = wave_reduce_sum(g1_3);

    if (lane == 0) {
        // jnp.argmax: first occurrence of max -> idx=1 only on strict g1 > g0
        {
            const int idx = (g1_0 > g0_0) ? 1 : 0;
            const float diff = idx ? (g0_0 - g1_0) : (g1_0 - g0_0);  // <= 0
            y[tbase + 0] = (1.0f / (1.0f + expf(diff))) * ((idx ? d1_0 : d0_0) + bsum[idx]);
        }
        {
            const int idx = (g1_1 > g0_1) ? 1 : 0;
            const float diff = idx ? (g0_1 - g1_1) : (g1_1 - g0_1);
            y[tbase + 1] = (1.0f / (1.0f + expf(diff))) * ((idx ? d1_1 : d0_1) + bsum[idx]);
        }
        {
            const int idx = (g1_2 > g0_2) ? 1 : 0;
            const float diff = idx ? (g0_2 - g1_2) : (g1_2 - g0_2);
            y[tbase + 2] = (1.0f / (1.0f + expf(diff))) * ((idx ? d1_2 : d0_2) + bsum[idx]);
        }
        {
            const int idx = (g1_3 > g0_3) ? 1 : 0;
            const float diff = idx ? (g0_3 - g1_3) : (g1_3 - g0_3);
            y[tbase + 3] = (1.0f / (1.0f + expf(diff))) * ((idx ? d1_3 : d0_3) + bsum[idx]);
        }
    }
}

// ---------- kernel 3: log_softmax over axis=1 (S) ----------
// One block per batch row; row held in registers (256 threads x f32x4).
__global__ __launch_bounds__(256) void logsoftmax_kernel(
        const float* __restrict__ y, float* __restrict__ out) {
    const int b = blockIdx.x;
    const f32x4* row4 = (const f32x4*)(y + (size_t)b * S_);
    f32x4 v = row4[threadIdx.x];

    float m = fmaxf(fmaxf(v.x, v.y), fmaxf(v.z, v.w));
    m = wave_reduce_max(m);
    __shared__ float lds[4];
    __shared__ float M_s, L_s;
    const int wave = threadIdx.x >> 6, lane = threadIdx.x & 63;
    if (lane == 0) lds[wave] = m;
    __syncthreads();
    if (threadIdx.x == 0)
        M_s = fmaxf(fmaxf(lds[0], lds[1]), fmaxf(lds[2], lds[3]));
    __syncthreads();
    const float M = M_s;

    float s = expf(v.x - M) + expf(v.y - M) + expf(v.z - M) + expf(v.w - M);
    s = wave_reduce_sum(s);
    __syncthreads();
    if (lane == 0) lds[wave] = s;
    __syncthreads();
    if (threadIdx.x == 0)
        L_s = M + logf(lds[0] + lds[1] + lds[2] + lds[3]);
    __syncthreads();
    const float lse = L_s;

    f32x4 o;
    o.x = v.x - lse; o.y = v.y - lse; o.z = v.z - lse; o.w = v.w - lse;
    ((f32x4*)(out + (size_t)b * S_))[threadIdx.x] = o;
}

extern "C" void kernel_launch(void* const* d_in, const int* in_sizes, int n_in,
                              void* d_out, int out_size, void* d_ws, size_t ws_size,
                              hipStream_t stream) {
    const float* x  = (const float*)d_in[0];   // [B,S,D]
    const float* wg = (const float*)d_in[1];   // [D,E]
    const float* W  = (const float*)d_in[2];   // [E,D,D]
    const float* bv = (const float*)d_in[3];   // [E,D]
    float* out = (float*)d_out;                // [B,S]

    float* ws   = (float*)d_ws;
    float* Wsum = ws;                  // E*D = 4096 floats
    float* bsum = ws + E_ * D_;        // 2 floats
    float* y    = ws + E_ * D_ + 16;   // B*S = 8192 floats (16B-aligned offset)

    reduce_rows_kernel<<<(NROWS + 3) / 4, 256, 0, stream>>>(W, bv, Wsum, bsum);
    token_kernel<<<B_ * S_ / 16, 256, 0, stream>>>(x, wg, Wsum, bsum, y);
    logsoftmax_kernel<<<B_, 256, 0, stream>>>(y, out);
}

// Round 12
// 25.698 us; speedup vs baseline: 1.0430x; 1.0430x over previous
//
#include <hip/hip_runtime.h>

#define B_ 8
#define S_ 1024
#define D_ 2048
#define E_ 2
#define NROWS (E_ * D_ + E_)   // 4098 reduction rows (W rows + bias rows)

typedef float f32x4 __attribute__((ext_vector_type(4)));

__device__ inline float wave_reduce_sum(float v) {
    #pragma unroll
    for (int off = 32; off > 0; off >>= 1) v += __shfl_down(v, off, 64);
    return v;
}
__device__ inline float wave_reduce_max(float v) {
    #pragma unroll
    for (int off = 32; off > 0; off >>= 1) v = fmaxf(v, __shfl_down(v, off, 64));
    return v;
}
__device__ inline float dot4(f32x4 a, f32x4 b) {
    return a.x * b.x + a.y * b.y + a.z * b.z + a.w * b.w;
}

// ---------- kernel 1: Wsum[e,d] = sum_h W[e,d,h]; bsum[e] = sum_h b[e,h] ----------
// One WAVE per row (D=2048 floats = 8 f32x4/lane). 4 waves/block, no barriers.
__global__ __launch_bounds__(256) void reduce_rows_kernel(
        const float* __restrict__ W, const float* __restrict__ bvec,
        float* __restrict__ Wsum, float* __restrict__ bsum) {
    const int wave = threadIdx.x >> 6, lane = threadIdx.x & 63;
    const int row = blockIdx.x * 4 + wave;
    if (row >= NROWS) return;
    const float* src = (row < E_ * D_) ? (W + (size_t)row * D_)
                                       : (bvec + (size_t)(row - E_ * D_) * D_);
    const f32x4* s4 = (const f32x4*)src;
    float s = 0.0f;
    #pragma unroll
    for (int j = 0; j < 8; ++j) {
        f32x4 v = __builtin_nontemporal_load(&s4[lane + j * 64]);  // W streamed once
        s += (v.x + v.y) + (v.z + v.w);
    }
    s = wave_reduce_sum(s);
    if (lane == 0) {
        if (row < E_ * D_) Wsum[row] = s;
        else               bsum[row - E_ * D_] = s;
    }
}

// ---------- kernel 2: per-token gate + selected-expert row-sum ----------
// R4 winner shape (1024 blocks, 2 tok/wave, 4 blocks/CU) + gate-DIFF trick:
// gate needs only gd = g1-g0 (idx = gd>0, gate = 1/(1+exp(-|gd|))), so stage
// one combined gate column instead of two: 3 LDS arrays (24 KB), 3 dot4/token.
__global__ __launch_bounds__(256) void token_kernel(
        const float* __restrict__ x, const float* __restrict__ wg,
        const float* __restrict__ Wsum, const float* __restrict__ bsum,
        float* __restrict__ y) {
    __shared__ float lw0[D_], lw1[D_], lgd[D_];            // 24 KB
    const int tid = threadIdx.x;

    // ---- stage: Wsum rows + gate-diff column (wg is [D,2] interleaved) ----
    {
        const f32x4* w0g = (const f32x4*)(Wsum);
        const f32x4* w1g = (const f32x4*)(Wsum + D_);
        const f32x4* wgg = (const f32x4*)(wg);
        f32x4* l0 = (f32x4*)lw0; f32x4* l1 = (f32x4*)lw1;
        f32x4* gd = (f32x4*)lgd;
        #pragma unroll
        for (int i = tid; i < D_ / 4; i += 256) {
            l0[i] = w0g[i];
            l1[i] = w1g[i];
            f32x4 u = wgg[2 * i];                          // d=4i..4i+1: (g0,g1,g0,g1)
            f32x4 v = wgg[2 * i + 1];                      // d=4i+2..4i+3
            f32x4 w;
            w.x = u.y - u.x; w.y = u.w - u.z;              // wg[:,1]-wg[:,0]
            w.z = v.y - v.x; w.w = v.w - v.z;
            gd[i] = w;
        }
    }
    __syncthreads();

    const int wave = tid >> 6, lane = tid & 63;
    const int t0 = blockIdx.x * 8 + wave * 2;              // 2 tokens per wave
    const int t1 = t0 + 1;
    const f32x4* xa = (const f32x4*)(x + (size_t)t0 * D_);
    const f32x4* xb = (const f32x4*)(x + (size_t)t1 * D_);
    const f32x4* l0r = (const f32x4*)lw0;
    const f32x4* l1r = (const f32x4*)lw1;
    const f32x4* gdr = (const f32x4*)lgd;

    float d0a = 0, d1a = 0, ga = 0;
    float d0b = 0, d1b = 0, gb = 0;
    #pragma unroll
    for (int j = 0; j < 8; ++j) {
        const int i = lane + j * 64;
        f32x4 x0 = __builtin_nontemporal_load(&xa[i]);     // x streamed once
        f32x4 x1 = __builtin_nontemporal_load(&xb[i]);
        f32x4 a = l0r[i], c = l1r[i], w = gdr[i];
        d0a += dot4(x0, a); d1a += dot4(x0, c); ga += dot4(x0, w);
        d0b += dot4(x1, a); d1b += dot4(x1, c); gb += dot4(x1, w);
    }
    d0a = wave_reduce_sum(d0a); d1a = wave_reduce_sum(d1a); ga = wave_reduce_sum(ga);
    d0b = wave_reduce_sum(d0b); d1b = wave_reduce_sum(d1b); gb = wave_reduce_sum(gb);

    if (lane == 0) {
        // idx = argmax first-occurrence: 1 iff strictly g1 > g0  <=>  gd > 0
        {
            const int idx = (ga > 0.0f) ? 1 : 0;
            const float gate = 1.0f / (1.0f + expf(-fabsf(ga)));
            y[t0] = gate * ((idx ? d1a : d0a) + bsum[idx]);
        }
        {
            const int idx = (gb > 0.0f) ? 1 : 0;
            const float gate = 1.0f / (1.0f + expf(-fabsf(gb)));
            y[t1] = gate * ((idx ? d1b : d0b) + bsum[idx]);
        }
    }
}

// ---------- kernel 3: log_softmax over axis=1 (S) ----------
// One block per batch row; row held in registers (256 threads x f32x4).
__global__ __launch_bounds__(256) void logsoftmax_kernel(
        const float* __restrict__ y, float* __restrict__ out) {
    const int b = blockIdx.x;
    const f32x4* row4 = (const f32x4*)(y + (size_t)b * S_);
    f32x4 v = row4[threadIdx.x];

    float m = fmaxf(fmaxf(v.x, v.y), fmaxf(v.z, v.w));
    m = wave_reduce_max(m);
    __shared__ float lds[4];
    __shared__ float M_s, L_s;
    const int wave = threadIdx.x >> 6, lane = threadIdx.x & 63;
    if (lane == 0) lds[wave] = m;
    __syncthreads();
    if (threadIdx.x == 0)
        M_s = fmaxf(fmaxf(lds[0], lds[1]), fmaxf(lds[2], lds[3]));
    __syncthreads();
    const float M = M_s;

    float s = expf(v.x - M) + expf(v.y - M) + expf(v.z - M) + expf(v.w - M);
    s = wave_reduce_sum(s);
    __syncthreads();
    if (lane == 0) lds[wave] = s;
    __syncthreads();
    if (threadIdx.x == 0)
        L_s = M + logf(lds[0] + lds[1] + lds[2] + lds[3]);
    __syncthreads();
    const float lse = L_s;

    f32x4 o;
    o.x = v.x - lse; o.y = v.y - lse; o.z = v.z - lse; o.w = v.w - lse;
    ((f32x4*)(out + (size_t)b * S_))[threadIdx.x] = o;
}

extern "C" void kernel_launch(void* const* d_in, const int* in_sizes, int n_in,
                              void* d_out, int out_size, void* d_ws, size_t ws_size,
                              hipStream_t stream) {
    const float* x  = (const float*)d_in[0];   // [B,S,D]
    const float* wg = (const float*)d_in[1];   // [D,E]
    const float* W  = (const float*)d_in[2];   // [E,D,D]
    const float* bv = (const float*)d_in[3];   // [E,D]
    float* out = (float*)d_out;                // [B,S]

    float* ws   = (float*)d_ws;
    float* Wsum = ws;                  // E*D = 4096 floats
    float* bsum = ws + E_ * D_;        // 2 floats
    float* y    = ws + E_ * D_ + 16;   // B*S = 8192 floats (16B-aligned offset)

    reduce_rows_kernel<<<(NROWS + 3) / 4, 256, 0, stream>>>(W, bv, Wsum, bsum);
    token_kernel<<<B_ * S_ / 8, 256, 0, stream>>>(x, wg, Wsum, bsum, y);
    logsoftmax_kernel<<<B_, 256, 0, stream>>>(y, out);
}